// Round 1
// baseline (54.958 us; speedup 1.0000x reference)
//
#include <hip/hip_runtime.h>
#include <hip/hip_bf16.h>

// ToroidalEmbedding:
//   idx:   (B,T)=(4,4096) int32      -> 16384 tokens
//   rho:   (50257, 1536) fp32
//   theta: (50257, 1536) fp32
//   gain:  (512, 2) fp32
//   out:   (B,T, 512*4) fp32 = (16384, 2048)
//
// Per token t, per block b (0..511):
//   r0..r2 = rho[idx[t], b*3 .. b*3+2]
//   t0..t2 = theta[idx[t], b*3 .. b*3+2]
//   s2 = sin(t2); c0,c1,c2 = cos(t0..t2)
//   sig0 = r0
//   sig1 = sig0 * (gain[b][0]*s2) + r1
//   sig2 = sig1 * (gain[b][1]*s2) + r2
//   out[t, b*4 .. b*4+3] = { sig0*c0, sig1*c1, sig2*c2, sig2*s2 }

#define N_BLOCKS 512
#define RANK 3
#define PPT (N_BLOCKS * RANK)      // 1536
#define OUT_PER_TOKEN (N_BLOCKS * 4) // 2048

__global__ __launch_bounds__(N_BLOCKS) void toroidal_embed_kernel(
    const int* __restrict__ idx,
    const float* __restrict__ rho,
    const float* __restrict__ theta,
    const float* __restrict__ gain,
    float* __restrict__ out,
    int n_tokens)
{
    const int token = blockIdx.x;
    if (token >= n_tokens) return;
    const int b = threadIdx.x;                 // toroid-block index 0..511

    const size_t row = (size_t)idx[token];     // scalar broadcast load
    const float* __restrict__ rp = rho   + row * PPT + (size_t)b * RANK;
    const float* __restrict__ tp = theta + row * PPT + (size_t)b * RANK;

    // 12 B/lane contiguous across the wave -> coalesced
    const float r0 = rp[0], r1 = rp[1], r2 = rp[2];
    const float t0 = tp[0], t1 = tp[1], t2 = tp[2];

    const float g0 = gain[b * 2 + 0];
    const float g1 = gain[b * 2 + 1];

    // theta in [0, 2pi): fast HW trig is plenty accurate for the 8.6e-2 threshold
    const float s2 = __sinf(t2);
    const float c0 = __cosf(t0);
    const float c1 = __cosf(t1);
    const float c2 = __cosf(t2);

    const float sig0 = r0;
    const float sig1 = fmaf(sig0, g0 * s2, r1);
    const float sig2 = fmaf(sig1, g1 * s2, r2);

    float4 o;
    o.x = sig0 * c0;
    o.y = sig1 * c1;
    o.z = sig2 * c2;
    o.w = sig2 * s2;

    // 16 B/lane aligned vector store -> perfectly coalesced
    *reinterpret_cast<float4*>(out + (size_t)token * OUT_PER_TOKEN + (size_t)b * 4) = o;
}

extern "C" void kernel_launch(void* const* d_in, const int* in_sizes, int n_in,
                              void* d_out, int out_size, void* d_ws, size_t ws_size,
                              hipStream_t stream)
{
    const int*   idx   = (const int*)d_in[0];
    const float* rho   = (const float*)d_in[1];
    const float* theta = (const float*)d_in[2];
    const float* gain  = (const float*)d_in[3];
    float*       out   = (float*)d_out;

    const int n_tokens = in_sizes[0];          // B*T = 16384

    dim3 grid(n_tokens);
    dim3 block(N_BLOCKS);
    toroidal_embed_kernel<<<grid, block, 0, stream>>>(idx, rho, theta, gain, out, n_tokens);
}

// Round 3
// 52.294 us; speedup vs baseline: 1.0509x; 1.0509x over previous
//
#include <hip/hip_runtime.h>
#include <hip/hip_bf16.h>

// ToroidalEmbedding:
//   idx:   (B,T)=(4,4096) int32      -> 16384 tokens
//   rho:   (50257, 1536) fp32
//   theta: (50257, 1536) fp32
//   gain:  (512, 2) fp32
//   out:   (B,T, 512*4) fp32 = (16384, 2048)
//
// Per token t, per block b (0..511):
//   r0..r2 = rho[idx[t], b*3 .. b*3+2]
//   t0..t2 = theta[idx[t], b*3 .. b*3+2]
//   s2 = sin(t2); c0,c1,c2 = cos(t0..t2)
//   sig0 = r0
//   sig1 = sig0 * (gain[b][0]*s2) + r1
//   sig2 = sig1 * (gain[b][1]*s2) + r2
//   out[t, b*4 .. b*4+3] = { sig0*c0, sig1*c1, sig2*c2, sig2*s2 }
//
// R3: non-temporal stores via native clang vector type (HIP float4 is a
// class and rejected by __builtin_nontemporal_store). Write-once output
// bypasses cache alloc -> preserves L2/L3 residency for rho/theta rows.

#define N_BLOCKS 512
#define RANK 3
#define PPT (N_BLOCKS * RANK)        // 1536
#define OUT_PER_TOKEN (N_BLOCKS * 4) // 2048

typedef float f32x4 __attribute__((ext_vector_type(4)));

__global__ __launch_bounds__(N_BLOCKS) void toroidal_embed_kernel(
    const int* __restrict__ idx,
    const float* __restrict__ rho,
    const float* __restrict__ theta,
    const float* __restrict__ gain,
    float* __restrict__ out,
    int n_tokens)
{
    const int token = blockIdx.x;
    if (token >= n_tokens) return;
    const int b = threadIdx.x;                 // toroid-block index 0..511

    const size_t row = (size_t)idx[token];     // scalar broadcast load
    const float* __restrict__ rp = rho   + row * PPT + (size_t)b * RANK;
    const float* __restrict__ tp = theta + row * PPT + (size_t)b * RANK;

    // 12 B/lane contiguous across the wave -> coalesced
    const float r0 = rp[0], r1 = rp[1], r2 = rp[2];
    const float t0 = tp[0], t1 = tp[1], t2 = tp[2];

    const float g0 = gain[b * 2 + 0];
    const float g1 = gain[b * 2 + 1];

    // theta in [0, 2pi): fast HW trig is plenty accurate for the 8.6e-2 threshold
    const float s2 = __sinf(t2);
    const float c0 = __cosf(t0);
    const float c1 = __cosf(t1);
    const float c2 = __cosf(t2);

    const float sig0 = r0;
    const float sig1 = fmaf(sig0, g0 * s2, r1);
    const float sig2 = fmaf(sig1, g1 * s2, r2);

    f32x4 o;
    o.x = sig0 * c0;
    o.y = sig1 * c1;
    o.z = sig2 * c2;
    o.w = sig2 * s2;

    // 16 B/lane aligned vector store, non-temporal (nt) -> bypass cache alloc
    __builtin_nontemporal_store(
        o, reinterpret_cast<f32x4*>(out + (size_t)token * OUT_PER_TOKEN + (size_t)b * 4));
}

extern "C" void kernel_launch(void* const* d_in, const int* in_sizes, int n_in,
                              void* d_out, int out_size, void* d_ws, size_t ws_size,
                              hipStream_t stream)
{
    const int*   idx   = (const int*)d_in[0];
    const float* rho   = (const float*)d_in[1];
    const float* theta = (const float*)d_in[2];
    const float* gain  = (const float*)d_in[3];
    float*       out   = (float*)d_out;

    const int n_tokens = in_sizes[0];          // B*T = 16384

    dim3 grid(n_tokens);
    dim3 block(N_BLOCKS);
    toroidal_embed_kernel<<<grid, block, 0, stream>>>(idx, rho, theta, gain, out, n_tokens);
}